// Round 1
// baseline (770.266 us; speedup 1.0000x reference)
//
#include <hip/hip_runtime.h>
#include <hip/hip_bf16.h>

typedef __bf16 bf16;
typedef __attribute__((ext_vector_type(8))) __bf16 bf16x8;
typedef __attribute__((ext_vector_type(4))) float f32x4;

// Pack B1 = [W1l | W1r] as [128 cols][128 k] bf16 (K-major, i.e. B^T form),
//      B2 = [W2l ; W2r] as [128 cols][128 k] bf16.
__global__ __launch_bounds__(256) void build_B_k(const float* __restrict__ W1l,
                                                 const float* __restrict__ W1r,
                                                 const float* __restrict__ W2l,
                                                 const float* __restrict__ W2r,
                                                 bf16* __restrict__ B1,
                                                 bf16* __restrict__ B2) {
  int gid = blockIdx.x * 256 + threadIdx.x;  // 0..32767
  if (gid < 16384) {
    int c = gid >> 7, k = gid & 127;
    float v = (k < 64) ? W1l[c * 64 + k] : W1r[c * 64 + (k - 64)];
    B1[gid] = (bf16)v;
  } else {
    int idx = gid - 16384;
    int n = idx >> 7, k = idx & 127;
    float v = (n < 64) ? W2l[n * 128 + k] : W2r[(n - 64) * 128 + k];
    B2[idx] = (bf16)v;
  }
}

__global__ __launch_bounds__(256) void deg_k(const int* __restrict__ dst,
                                             float* __restrict__ deg, int E) {
  int e = blockIdx.x * 256 + threadIdx.x;
  if (e < E) atomicAdd(deg + dst[e], 1.0f);
}

// 64 threads per edge: gather x[src] row, atomic-add into agg[dst] row.
__global__ __launch_bounds__(256) void scatter1_k(const float* __restrict__ x,
                                                  const int* __restrict__ src,
                                                  const int* __restrict__ dst,
                                                  float* __restrict__ agg, int E) {
  long gid = (long)blockIdx.x * 256 + threadIdx.x;
  int e = (int)(gid >> 6);
  if (e >= E) return;
  int c = (int)(gid & 63);
  atomicAdd(agg + (long)dst[e] * 64 + c, x[(long)src[e] * 64 + c]);
}

// A1[n][k] = bf16( k<64 ? agg[n][k]/max(deg,1) : x[n][k-64] ), pad rows -> 0
__global__ __launch_bounds__(256) void prepA_k(const float* __restrict__ agg,
                                               const float* __restrict__ deg,
                                               const float* __restrict__ x,
                                               bf16* __restrict__ A1, int N, int Np) {
  long gid = (long)blockIdx.x * 256 + threadIdx.x;
  int n = (int)(gid >> 7);
  if (n >= Np) return;
  int k = (int)(gid & 127);
  float v;
  if (k < 64) {
    v = agg[(long)n * 64 + k] * (1.0f / fmaxf(deg[n], 1.0f));  // agg/deg zero-padded
  } else {
    v = (n < N) ? x[(long)n * 64 + (k - 64)] : 0.0f;
  }
  A1[gid] = (bf16)v;
}

// C[Mp x 128] = A[Mp x 128] * B^T, B stored [128 cols][128 k] bf16.
// Per block: 128 rows (4 waves x 32 rows). B frags held in registers.
__global__ __launch_bounds__(256) void gemm_bf16_k(const bf16* __restrict__ A,
                                                   const bf16* __restrict__ B,
                                                   bf16* __restrict__ C,
                                                   const float* __restrict__ bias,
                                                   int relu) {
  int wave = threadIdx.x >> 6;
  int lane = threadIdx.x & 63;
  int row = lane & 15;   // m within 16-tile (A), col within 16-tile (C/D, B)
  int quad = lane >> 4;  // 0..3
  long mbase = (long)blockIdx.x * 128 + (long)wave * 32;

  // B fragments: 8 col-tiles x 4 k-steps, 8 bf16 each
  bf16x8 bfrag[8][4];
#pragma unroll
  for (int j = 0; j < 8; j++)
#pragma unroll
    for (int s = 0; s < 4; s++)
      bfrag[j][s] = *(const bf16x8*)(B + (long)(j * 16 + row) * 128 + s * 32 + quad * 8);

  f32x4 acc[2][8] = {};
#pragma unroll
  for (int s = 0; s < 4; s++) {
    bf16x8 a0 = *(const bf16x8*)(A + (mbase + row) * 128 + s * 32 + quad * 8);
    bf16x8 a1 = *(const bf16x8*)(A + (mbase + 16 + row) * 128 + s * 32 + quad * 8);
#pragma unroll
    for (int j = 0; j < 8; j++) {
      acc[0][j] = __builtin_amdgcn_mfma_f32_16x16x32_bf16(a0, bfrag[j][s], acc[0][j], 0, 0, 0);
      acc[1][j] = __builtin_amdgcn_mfma_f32_16x16x32_bf16(a1, bfrag[j][s], acc[1][j], 0, 0, 0);
    }
  }

  // C/D layout: col = lane&15, row-in-tile = quad*4 + i
#pragma unroll
  for (int r = 0; r < 2; r++) {
    long rb = mbase + r * 16;
#pragma unroll
    for (int j = 0; j < 8; j++) {
      int col = j * 16 + row;
      float bv = bias ? bias[col] : 0.0f;
#pragma unroll
      for (int i = 0; i < 4; i++) {
        float v = acc[r][j][i] + bv;
        if (relu) v = v > 0.0f ? v : 0.0f;
        C[(rb + quad * 4 + i) * 128 + col] = (bf16)v;
      }
    }
  }
}

// scatter of t = tu[:, 0:64] (bf16) into agg2 (f32 atomics)
__global__ __launch_bounds__(256) void scatter2_k(const bf16* __restrict__ tu,
                                                  const int* __restrict__ src,
                                                  const int* __restrict__ dst,
                                                  float* __restrict__ agg, int E) {
  long gid = (long)blockIdx.x * 256 + threadIdx.x;
  int e = (int)(gid >> 6);
  if (e >= E) return;
  int c = (int)(gid & 63);
  atomicAdd(agg + (long)dst[e] * 64 + c, (float)tu[(long)src[e] * 128 + c]);
}

// out = agg2/max(deg,1) + b2l + u,  u = tu[:, 64:128]
__global__ __launch_bounds__(256) void final_k(const float* __restrict__ agg,
                                               const float* __restrict__ deg,
                                               const bf16* __restrict__ tu,
                                               const float* __restrict__ b2l,
                                               float* __restrict__ out, int N) {
  long gid = (long)blockIdx.x * 256 + threadIdx.x;
  int n = (int)(gid >> 6);
  if (n >= N) return;
  int c = (int)(gid & 63);
  out[gid] = agg[gid] * (1.0f / fmaxf(deg[n], 1.0f)) + b2l[c] + (float)tu[(long)n * 128 + 64 + c];
}

extern "C" void kernel_launch(void* const* d_in, const int* in_sizes, int n_in,
                              void* d_out, int out_size, void* d_ws, size_t ws_size,
                              hipStream_t stream) {
  const float* x = (const float*)d_in[0];
  const int* edge_index = (const int*)d_in[1];
  const float* W1l = (const float*)d_in[2];
  const float* b1l = (const float*)d_in[3];
  const float* W1r = (const float*)d_in[4];
  const float* W2l = (const float*)d_in[5];
  const float* b2l = (const float*)d_in[6];
  const float* W2r = (const float*)d_in[7];

  const int N = in_sizes[0] / 64;       // 100000
  const int E = in_sizes[1] / 2;        // 1200000
  const int Np = (N + 127) / 128 * 128; // 100096

  const int* src = edge_index;
  const int* dst = edge_index + E;

  // workspace layout (256B aligned)
  char* ws = (char*)d_ws;
  size_t o_deg = 0;
  size_t o_agg = ((size_t)Np * 4 + 255) / 256 * 256;            // deg: Np f32
  size_t o_A1tu = o_agg + (size_t)Np * 64 * 4;                  // agg: Np x 64 f32 (reused as agg2)
  size_t o_h = o_A1tu + (size_t)Np * 128 * 2;                   // A1 (bf16), later reused as tu
  size_t o_B1 = o_h + (size_t)Np * 128 * 2;                     // h: Np x 128 bf16
  size_t o_B2 = o_B1 + 128 * 128 * 2;

  float* deg = (float*)(ws + o_deg);
  float* agg = (float*)(ws + o_agg);
  bf16* A1 = (bf16*)(ws + o_A1tu);
  bf16* tu = (bf16*)(ws + o_A1tu);  // reuses A1 space (A1 dead after gemm1)
  bf16* h = (bf16*)(ws + o_h);
  bf16* B1 = (bf16*)(ws + o_B1);
  bf16* B2 = (bf16*)(ws + o_B2);
  float* out = (float*)d_out;

  // zero deg + agg1 (contiguous region)
  hipMemsetAsync(ws, 0, o_A1tu, stream);

  build_B_k<<<128, 256, 0, stream>>>(W1l, W1r, W2l, W2r, B1, B2);
  deg_k<<<(E + 255) / 256, 256, 0, stream>>>(dst, deg, E);
  scatter1_k<<<(int)(((long)E * 64 + 255) / 256), 256, 0, stream>>>(x, src, dst, agg, E);
  prepA_k<<<(int)(((long)Np * 128 + 255) / 256), 256, 0, stream>>>(agg, deg, x, A1, N, Np);
  gemm_bf16_k<<<Np / 128, 256, 0, stream>>>(A1, B1, h, b1l, 1);
  gemm_bf16_k<<<Np / 128, 256, 0, stream>>>(h, B2, tu, nullptr, 0);
  // re-zero agg region -> becomes agg2
  hipMemsetAsync(ws + o_agg, 0, (size_t)Np * 64 * 4, stream);
  scatter2_k<<<(int)(((long)E * 64 + 255) / 256), 256, 0, stream>>>(tu, src, dst, agg, E);
  final_k<<<(int)(((long)N * 64 + 255) / 256), 256, 0, stream>>>(agg, deg, tu, b2l, out, N);
}

// Round 2
// 434.013 us; speedup vs baseline: 1.7748x; 1.7748x over previous
//
#include <hip/hip_runtime.h>
#include <hip/hip_bf16.h>

typedef __bf16 bf16;
typedef __attribute__((ext_vector_type(8))) __bf16 bf16x8;
typedef __attribute__((ext_vector_type(4))) float f32x4;

// Pack B1 = [W1l | W1r] as [128 cols][128 k] bf16 (K-major, i.e. B^T form),
//      B2 = [W2l ; W2r] as [128 cols][128 k] bf16.
__global__ __launch_bounds__(256) void build_B_k(const float* __restrict__ W1l,
                                                 const float* __restrict__ W1r,
                                                 const float* __restrict__ W2l,
                                                 const float* __restrict__ W2r,
                                                 bf16* __restrict__ B1,
                                                 bf16* __restrict__ B2) {
  int gid = blockIdx.x * 256 + threadIdx.x;  // 0..32767
  if (gid < 16384) {
    int c = gid >> 7, k = gid & 127;
    float v = (k < 64) ? W1l[c * 64 + k] : W1r[c * 64 + (k - 64)];
    B1[gid] = (bf16)v;
  } else {
    int idx = gid - 16384;
    int n = idx >> 7, k = idx & 127;
    float v = (n < 64) ? W2l[n * 128 + k] : W2r[(n - 64) * 128 + k];
    B2[idx] = (bf16)v;
  }
}

// ---- CSR build ----
__global__ __launch_bounds__(256) void degcount_k(const int* __restrict__ dst,
                                                  int* __restrict__ deg, int E) {
  int e = blockIdx.x * 256 + threadIdx.x;
  if (e < E) atomicAdd(deg + dst[e], 1);
}

// per-block exclusive scan of deg -> partial, block total -> blocksum
__global__ __launch_bounds__(256) void scan1_k(const int* __restrict__ deg,
                                               int* __restrict__ partial,
                                               int* __restrict__ blocksum, int N) {
  __shared__ int sd[256];
  int t = threadIdx.x;
  int idx = blockIdx.x * 256 + t;
  int v = (idx < N) ? deg[idx] : 0;
  sd[t] = v;
  __syncthreads();
#pragma unroll
  for (int off = 1; off < 256; off <<= 1) {
    int tv = (t >= off) ? sd[t - off] : 0;
    __syncthreads();
    if (t >= off) sd[t] += tv;
    __syncthreads();
  }
  if (idx < N) partial[idx] = sd[t] - v;
  if (t == 255) blocksum[blockIdx.x] = sd[255];
}

// single-block exclusive scan of blocksum (NB <= 512)
__global__ __launch_bounds__(512) void scan2_k(const int* __restrict__ blocksum,
                                               int* __restrict__ blockoff, int NB) {
  __shared__ int sd[512];
  int t = threadIdx.x;
  int v = (t < NB) ? blocksum[t] : 0;
  sd[t] = v;
  __syncthreads();
#pragma unroll
  for (int off = 1; off < 512; off <<= 1) {
    int tv = (t >= off) ? sd[t - off] : 0;
    __syncthreads();
    if (t >= off) sd[t] += tv;
    __syncthreads();
  }
  if (t < NB) blockoff[t] = sd[t] - v;
}

__global__ __launch_bounds__(256) void scan3_k(const int* __restrict__ partial,
                                               const int* __restrict__ blockoff,
                                               int* __restrict__ rowptr,
                                               int* __restrict__ cursor, int N, int E) {
  int idx = blockIdx.x * 256 + threadIdx.x;
  if (idx < N) {
    int r = partial[idx] + blockoff[idx >> 8];
    rowptr[idx] = r;
    cursor[idx] = r;
  }
  if (idx == 0) rowptr[N] = E;
}

__global__ __launch_bounds__(256) void fill_k(const int* __restrict__ src,
                                              const int* __restrict__ dst,
                                              int* __restrict__ cursor,
                                              int* __restrict__ nbr, int E) {
  int e = blockIdx.x * 256 + threadIdx.x;
  if (e >= E) return;
  int pos = atomicAdd(cursor + dst[e], 1);
  nbr[pos] = src[e];
}

// ---- layer 1 aggregation fused with A-matrix build ----
// wave per node; lane = feature col. A1[n] = [mean(x[nbr]) | x[n]] in bf16.
__global__ __launch_bounds__(256) void agg1_k(const float* __restrict__ x,
                                              const int* __restrict__ rowptr,
                                              const int* __restrict__ nbr,
                                              bf16* __restrict__ A1, int N, int Np) {
  int wave = threadIdx.x >> 6, lane = threadIdx.x & 63;
  int n = blockIdx.x * 4 + wave;
  if (n >= Np) return;
  long ab = (long)n * 128;
  if (n >= N) {
    A1[ab + lane] = (bf16)0.0f;
    A1[ab + 64 + lane] = (bf16)0.0f;
    return;
  }
  int s = rowptr[n], e = rowptr[n + 1];
  float sum = 0.0f;
  int i = s;
  for (; i + 1 < e; i += 2) {
    int j0 = nbr[i], j1 = nbr[i + 1];
    float v0 = x[(long)j0 * 64 + lane];
    float v1 = x[(long)j1 * 64 + lane];
    sum += v0 + v1;
  }
  if (i < e) sum += x[(long)nbr[i] * 64 + lane];
  float mean = sum / fmaxf((float)(e - s), 1.0f);
  A1[ab + lane] = (bf16)mean;
  A1[ab + 64 + lane] = (bf16)x[(long)n * 64 + lane];
}

// C[Mp x 128] = A[Mp x 128] * B^T, B stored [128 cols][128 k] bf16.
// Per block: 128 rows (4 waves x 32 rows). B frags held in registers.
__global__ __launch_bounds__(256) void gemm_bf16_k(const bf16* __restrict__ A,
                                                   const bf16* __restrict__ B,
                                                   bf16* __restrict__ C,
                                                   const float* __restrict__ bias,
                                                   int relu) {
  int wave = threadIdx.x >> 6;
  int lane = threadIdx.x & 63;
  int row = lane & 15;
  int quad = lane >> 4;
  long mbase = (long)blockIdx.x * 128 + (long)wave * 32;

  bf16x8 bfrag[8][4];
#pragma unroll
  for (int j = 0; j < 8; j++)
#pragma unroll
    for (int s = 0; s < 4; s++)
      bfrag[j][s] = *(const bf16x8*)(B + (long)(j * 16 + row) * 128 + s * 32 + quad * 8);

  f32x4 acc[2][8] = {};
#pragma unroll
  for (int s = 0; s < 4; s++) {
    bf16x8 a0 = *(const bf16x8*)(A + (mbase + row) * 128 + s * 32 + quad * 8);
    bf16x8 a1 = *(const bf16x8*)(A + (mbase + 16 + row) * 128 + s * 32 + quad * 8);
#pragma unroll
    for (int j = 0; j < 8; j++) {
      acc[0][j] = __builtin_amdgcn_mfma_f32_16x16x32_bf16(a0, bfrag[j][s], acc[0][j], 0, 0, 0);
      acc[1][j] = __builtin_amdgcn_mfma_f32_16x16x32_bf16(a1, bfrag[j][s], acc[1][j], 0, 0, 0);
    }
  }

#pragma unroll
  for (int r = 0; r < 2; r++) {
    long rb = mbase + r * 16;
#pragma unroll
    for (int j = 0; j < 8; j++) {
      int col = j * 16 + row;
      float bv = bias ? bias[col] : 0.0f;
#pragma unroll
      for (int i = 0; i < 4; i++) {
        float v = acc[r][j][i] + bv;
        if (relu) v = v > 0.0f ? v : 0.0f;
        C[(rb + quad * 4 + i) * 128 + col] = (bf16)v;
      }
    }
  }
}

// ---- layer 2 aggregation fused with bias + root add + output ----
// out[n][c] = mean_j tu[j][c] + b2l[c] + tu[n][64+c]
__global__ __launch_bounds__(256) void agg2_k(const bf16* __restrict__ tu,
                                              const int* __restrict__ rowptr,
                                              const int* __restrict__ nbr,
                                              const float* __restrict__ b2l,
                                              float* __restrict__ out, int N) {
  int wave = threadIdx.x >> 6, lane = threadIdx.x & 63;
  int n = blockIdx.x * 4 + wave;
  if (n >= N) return;
  int s = rowptr[n], e = rowptr[n + 1];
  float sum = 0.0f;
  int i = s;
  for (; i + 1 < e; i += 2) {
    int j0 = nbr[i], j1 = nbr[i + 1];
    sum += (float)tu[(long)j0 * 128 + lane] + (float)tu[(long)j1 * 128 + lane];
  }
  if (i < e) sum += (float)tu[(long)nbr[i] * 128 + lane];
  out[(long)n * 64 + lane] =
      sum / fmaxf((float)(e - s), 1.0f) + b2l[lane] + (float)tu[(long)n * 128 + 64 + lane];
}

static inline size_t align256(size_t x) { return (x + 255) / 256 * 256; }

extern "C" void kernel_launch(void* const* d_in, const int* in_sizes, int n_in,
                              void* d_out, int out_size, void* d_ws, size_t ws_size,
                              hipStream_t stream) {
  const float* x = (const float*)d_in[0];
  const int* edge_index = (const int*)d_in[1];
  const float* W1l = (const float*)d_in[2];
  const float* b1l = (const float*)d_in[3];
  const float* W1r = (const float*)d_in[4];
  const float* W2l = (const float*)d_in[5];
  const float* b2l = (const float*)d_in[6];
  const float* W2r = (const float*)d_in[7];

  const int N = in_sizes[0] / 64;        // 100000
  const int E = in_sizes[1] / 2;         // 1200000
  const int Np = (N + 127) / 128 * 128;  // 100096
  const int NB = (N + 255) / 256;        // 391

  const int* src = edge_index;
  const int* dst = edge_index + E;

  char* ws = (char*)d_ws;
  size_t off = 0;
  int* deg = (int*)(ws + off);       off += align256((size_t)Np * 4);
  int* partial = (int*)(ws + off);   off += align256((size_t)Np * 4);
  int* blocksum = (int*)(ws + off);  off += align256((size_t)NB * 4);
  int* blockoff = (int*)(ws + off);  off += align256((size_t)NB * 4);
  int* rowptr = (int*)(ws + off);    off += align256((size_t)(Np + 1) * 4);
  int* cursor = (int*)(ws + off);    off += align256((size_t)Np * 4);
  int* nbr = (int*)(ws + off);       off += align256((size_t)E * 4);
  bf16* A1 = (bf16*)(ws + off);      // reused as tu after gemm2
  bf16* tu = (bf16*)(ws + off);      off += align256((size_t)Np * 128 * 2);
  bf16* h = (bf16*)(ws + off);       off += align256((size_t)Np * 128 * 2);
  bf16* B1 = (bf16*)(ws + off);      off += align256(128 * 128 * 2);
  bf16* B2 = (bf16*)(ws + off);      off += align256(128 * 128 * 2);
  float* out = (float*)d_out;

  // zero degree counts only
  hipMemsetAsync(deg, 0, (size_t)Np * 4, stream);

  build_B_k<<<128, 256, 0, stream>>>(W1l, W1r, W2l, W2r, B1, B2);
  degcount_k<<<(E + 255) / 256, 256, 0, stream>>>(dst, deg, E);
  scan1_k<<<NB, 256, 0, stream>>>(deg, partial, blocksum, N);
  scan2_k<<<1, 512, 0, stream>>>(blocksum, blockoff, NB);
  scan3_k<<<NB, 256, 0, stream>>>(partial, blockoff, rowptr, cursor, N, E);
  fill_k<<<(E + 255) / 256, 256, 0, stream>>>(src, dst, cursor, nbr, E);

  agg1_k<<<Np / 4, 256, 0, stream>>>(x, rowptr, nbr, A1, N, Np);
  gemm_bf16_k<<<Np / 128, 256, 0, stream>>>(A1, B1, h, b1l, 1);
  gemm_bf16_k<<<Np / 128, 256, 0, stream>>>(h, B2, tu, nullptr, 0);
  agg2_k<<<(N + 3) / 4, 256, 0, stream>>>(tu, rowptr, nbr, b2l, out, N);
}